// Round 17
// baseline (194.293 us; speedup 1.0000x reference)
//
#include <hip/hip_runtime.h>
#include <hip/hip_bf16.h>

typedef __attribute__((ext_vector_type(4))) float f32x4;
typedef __attribute__((ext_vector_type(8))) short s16x8;
typedef __attribute__((ext_vector_type(4))) int i32x4;
typedef __attribute__((ext_vector_type(4))) unsigned short u16x4;

#define NEG_INF_F (-9.0e15f)
#define LOG2E_F 1.44269504088896340736f
#define N_ROWS 8192
#define F_DIM 256

__device__ __forceinline__ unsigned short f2bf(float f) {
    unsigned int u = __builtin_bit_cast(unsigned int, f);
    u += 0x7fffu + ((u >> 16) & 1u);   // round-to-nearest-even
    return (unsigned short)(u >> 16);
}

__device__ __forceinline__ float fast_exp2(float x) {
#if __has_builtin(__builtin_amdgcn_exp2f)
    return __builtin_amdgcn_exp2f(x);   // raw v_exp_f32; big-neg -> exactly 0.0
#else
    return exp2f(x);
#endif
}

__device__ __forceinline__ short f2bf_fast(float f) {
    __hip_bfloat16 b = __float2bfloat16(f);   // native cast -> v_cvt_pk_bf16_f32 pairs
    return __builtin_bit_cast(short, b);
}

// ------------- Kernel 0: pack adj -> bitmask (ballot, coalesced) ---------
// Output bit order proven identical to the per-thread packer (r6 == r7).
__global__ __launch_bounds__(256) void k0_pack(const int* __restrict__ adj,
                                               unsigned long long* __restrict__ mask) {
    const int lane = threadIdx.x & 63;
    const int gw = ((int)blockIdx.x * 256 + (int)threadIdx.x) >> 6;
    const int nw = ((int)gridDim.x * 256) >> 6;
#pragma unroll 1
    for (int w4 = gw * 4; w4 < (N_ROWS * N_ROWS / 64); w4 += nw * 4) {
        const size_t base = (size_t)w4 * 64 + lane;
        const int v0 = adj[base];
        const int v1 = adj[base + 64];
        const int v2 = adj[base + 128];
        const int v3 = adj[base + 192];
        const unsigned long long b0 = __ballot(v0 > 0);
        const unsigned long long b1 = __ballot(v1 > 0);
        const unsigned long long b2 = __ballot(v2 > 0);
        const unsigned long long b3 = __ballot(v3 > 0);
        if (lane == 0) {
            mask[w4] = b0; mask[w4 + 1] = b1; mask[w4 + 2] = b2; mask[w4 + 3] = b3;
        }
    }
}

// ------------- Kernel 1: hTp = bf16(x @ W^T), packed [k/8][feat][k%8] ----
__global__ __launch_bounds__(256) void k1_gemm(const float* __restrict__ x,
                                               const float* __restrict__ W,
                                               unsigned short* __restrict__ hTp) {
    __shared__ float xT[128][64];
    __shared__ float wT[128][64];
    const int tid = threadIdx.x;
    const int rb = blockIdx.x >> 2, fbk = blockIdx.x & 3;
    const int row0 = rb * 64, f0 = fbk * 64;
    const int rs = tid >> 2, cs = tid & 3;
    const int r0 = (tid & 15) * 4, fc = (tid >> 4) * 4;
    float acc[4][4];
#pragma unroll
    for (int i = 0; i < 4; ++i)
#pragma unroll
        for (int j = 0; j < 4; ++j) acc[i][j] = 0.0f;

#pragma unroll 1
    for (int p = 0; p < 2; ++p) {
        const int kb = p * 128;
        if (p) __syncthreads();
        const float* xrow = x + (size_t)(row0 + rs) * F_DIM + kb + cs * 32;
        const float* wrow = W + (size_t)(f0 + rs) * F_DIM + kb + cs * 32;
#pragma unroll
        for (int i = 0; i < 8; ++i) {
            f32x4 xv = *(const f32x4*)(xrow + i * 4);
            f32x4 wv = *(const f32x4*)(wrow + i * 4);
#pragma unroll
            for (int jj = 0; jj < 4; ++jj) {
                xT[cs * 32 + i * 4 + jj][rs] = xv[jj];
                wT[cs * 32 + i * 4 + jj][rs] = wv[jj];
            }
        }
        __syncthreads();
#pragma unroll 4
        for (int kk = 0; kk < 128; ++kk) {
            f32x4 xv = *(const f32x4*)&xT[kk][r0];
            f32x4 wv = *(const f32x4*)&wT[kk][fc];
#pragma unroll
            for (int i = 0; i < 4; ++i)
#pragma unroll
                for (int j = 0; j < 4; ++j)
                    acc[i][j] = fmaf(xv[i], wv[j], acc[i][j]);
        }
    }
    const int kblk = (row0 + r0) >> 3, kslot = (row0 + r0) & 7;
#pragma unroll
    for (int j = 0; j < 4; ++j) {
        u16x4 t;
        t[0] = f2bf(acc[0][j]); t[1] = f2bf(acc[1][j]);
        t[2] = f2bf(acc[2][j]); t[3] = f2bf(acc[3][j]);
        *(u16x4*)(hTp + (size_t)kblk * 2048 + (f0 + fc + j) * 8 + kslot) = t;
    }
}

// ------------- Kernel 1a: va1 = W^T a1, va2 = W^T a2 ---------------------
__global__ __launch_bounds__(256) void kva(const float* __restrict__ W,
                                           const float* __restrict__ a,
                                           float* __restrict__ va) {
    const int k = threadIdx.x;
    const int b = blockIdx.x;
    const float* av = a + b * 256;
    float s0 = 0.f, s1 = 0.f, s2 = 0.f, s3 = 0.f;
#pragma unroll 8
    for (int f = 0; f < 256; f += 4) {
        s0 = fmaf(av[f],     W[(size_t)f * 256 + k],       s0);
        s1 = fmaf(av[f + 1], W[(size_t)(f + 1) * 256 + k], s1);
        s2 = fmaf(av[f + 2], W[(size_t)(f + 2) * 256 + k], s2);
        s3 = fmaf(av[f + 3], W[(size_t)(f + 3) * 256 + k], s3);
    }
    va[b * 256 + k] = (s0 + s1) + (s2 + s3);
}

// ------------- Kernel 1b: s1 = x@va1, s2 = x@va2 (f32) -------------------
__global__ __launch_bounds__(256) void k1b_s(const float* __restrict__ x,
                                             const float* __restrict__ va,
                                             float* __restrict__ s1,
                                             float* __restrict__ s2) {
    const int tid = threadIdx.x, lane = tid & 63, w = tid >> 6;
    f32x4 a1 = *(const f32x4*)(va + lane * 4);
    f32x4 a2 = *(const f32x4*)(va + 256 + lane * 4);
    const int row0 = blockIdx.x * 32 + w * 8;
#pragma unroll 1
    for (int rr = 0; rr < 8; ++rr) {
        const int row = row0 + rr;
        f32x4 hv = *(const f32x4*)(x + (size_t)row * F_DIM + lane * 4);
        float p1 = hv[0] * a1[0] + hv[1] * a1[1] + hv[2] * a1[2] + hv[3] * a1[3];
        float p2 = hv[0] * a2[0] + hv[1] * a2[1] + hv[2] * a2[2] + hv[3] * a2[3];
#pragma unroll
        for (int o = 32; o; o >>= 1) { p1 += __shfl_xor(p1, o); p2 += __shfl_xor(p2, o); }
        if (lane == 0) { s1[row] = p1; s2[row] = p2; }
    }
}

// ------------- Kernel 1c: M[i] = max over unmasked j of s2[j] ------------
__global__ __launch_bounds__(256) void kmax(const unsigned* __restrict__ mask32,
                                            const float* __restrict__ s2,
                                            float* __restrict__ Mrow) {
    __shared__ float s2l[8192];
    const int tid = threadIdx.x, lane = tid & 63, wv = tid >> 6;
#pragma unroll
    for (int i = 0; i < 8; ++i) {
        const int idx = (i * 256 + tid) * 4;
        *(f32x4*)&s2l[idx] = *(const f32x4*)(s2 + idx);
    }
    __syncthreads();
    const int row = (int)blockIdx.x * 4 + wv;
    const unsigned* __restrict__ mr = mask32 + (size_t)row * 256;
    float vmax = NEG_INF_F;
#pragma unroll 1
    for (int wi = 0; wi < 4; ++wi) {
        const unsigned m = mr[lane * 4 + wi];
        const int kb = (lane * 4 + wi) * 32;
#pragma unroll
        for (int cc = 0; cc < 8; ++cc) {
            const int c = (cc + lane) & 7;
            f32x4 v = *(const f32x4*)&s2l[kb + c * 4];
            const unsigned sh = (unsigned)(c * 4);
            vmax = fmaxf(vmax, ((m >> (sh + 0)) & 1u) ? v[0] : NEG_INF_F);
            vmax = fmaxf(vmax, ((m >> (sh + 1)) & 1u) ? v[1] : NEG_INF_F);
            vmax = fmaxf(vmax, ((m >> (sh + 2)) & 1u) ? v[2] : NEG_INF_F);
            vmax = fmaxf(vmax, ((m >> (sh + 3)) & 1u) ? v[3] : NEG_INF_F);
        }
    }
#pragma unroll
    for (int o = 32; o; o >>= 1) vmax = fmaxf(vmax, __shfl_xor(vmax, o));
    if (lane == 0) Mrow[row] = vmax;
}

// ------------- Kernel 2: fused masked softmax + PV (LDS-staged B) --------
// Grid 512 = 128 rowblocks(64 rows) x 2 fh x 2 ks; 2 blk/CU (LDS 64KB each).
// 4 waves = 4 ROW-GROUPS of 16 (not key-chunks!) -> all waves share the same
// B-tile, staged once in LDS (dbuf, 128-key tiles, reg-staged, 1 barrier/tile,
// prefetch 2 tiles ahead). No cross-wave merge: each wave stores its own rows.
// ks=0 -> out (unnormalized), ks=1 -> p1; Lp partials; k3 merges.

#define P_ONE(D, SV, BIT, SI, MC)                                             \
    { float t_ = (SI) + (SV); t_ = fmaxf(t_, 0.2f * t_);                      \
      D = fast_exp2(fmaf(((bb_ & (BIT)) ? t_ : NEG_INF_F), LOG2E_F, -(MC))); }

#define LOADREGS(TILE)                                                        \
    {                                                                         \
        const unsigned kb = (unsigned)(((unsigned)(ksbase + (TILE) * 128) >> 3) + ch) * 2048u \
                          + (unsigned)(fb * 8) + (unsigned)off;               \
        _Pragma("unroll")                                                     \
        for (int i_ = 0; i_ < 8; ++i_)                                        \
            sreg[i_] = *(const i32x4*)(hTp + kb + (unsigned)(i_ * 128));      \
    }

#define WRITELDS(BUF)                                                         \
    {                                                                         \
        short* p_ = &lds[BUF][ch * 1024 + off];                               \
        _Pragma("unroll")                                                     \
        for (int i_ = 0; i_ < 8; ++i_)                                        \
            *(i32x4*)(p_ + i_ * 128) = sreg[i_];                              \
    }

#define STEP(S)                                                               \
    {                                                                         \
        const int k0 = ksbase + t * 128 + (S) * 32;                           \
        const unsigned mw = (unsigned)mwv[(S)];                               \
        const f32x4 svA_ = *(const f32x4*)(s2 + k0 + koff);                   \
        const f32x4 svB_ = *(const f32x4*)(s2 + k0 + koff + 4);               \
        s16x8 bfr[8];                                                         \
        _Pragma("unroll")                                                     \
        for (int nt_ = 0; nt_ < 8; ++nt_)                                     \
            bfr[nt_] = *(const s16x8*)&lds[cur][((S) * 4 + kg) * 1024 + (nt_ * 16 + lane15) * 8]; \
        const unsigned bb_ = (mw >> koff) & 0xffu;                            \
        float p0_, p1_, p2_, p3_, p4_, p5_, p6_, p7_;                         \
        P_ONE(p0_, svA_[0], 1u, si, mC)   P_ONE(p1_, svA_[1], 2u, si, mC)     \
        P_ONE(p2_, svA_[2], 4u, si, mC)   P_ONE(p3_, svA_[3], 8u, si, mC)     \
        P_ONE(p4_, svB_[0], 16u, si, mC)  P_ONE(p5_, svB_[1], 32u, si, mC)    \
        P_ONE(p6_, svB_[2], 64u, si, mC)  P_ONE(p7_, svB_[3], 128u, si, mC)   \
        s16x8 af_;                                                            \
        af_[0] = f2bf_fast(p0_); af_[1] = f2bf_fast(p1_);                     \
        af_[2] = f2bf_fast(p2_); af_[3] = f2bf_fast(p3_);                     \
        af_[4] = f2bf_fast(p4_); af_[5] = f2bf_fast(p5_);                     \
        af_[6] = f2bf_fast(p6_); af_[7] = f2bf_fast(p7_);                     \
        _Pragma("unroll")                                                     \
        for (int nt_ = 0; nt_ < 8; ++nt_)                                     \
            acc[nt_] = __builtin_amdgcn_mfma_f32_16x16x32_bf16(af_, bfr[nt_], acc[nt_], 0, 0, 0); \
        accL = __builtin_amdgcn_mfma_f32_16x16x32_bf16(af_, bones, accL, 0, 0, 0); \
    }

__global__ __launch_bounds__(256) void k2_attn(const unsigned* __restrict__ mask32,
                                               const unsigned short* __restrict__ hTp,
                                               const float* __restrict__ s1,
                                               const float* __restrict__ s2,
                                               const float* __restrict__ Mrow,
                                               float* __restrict__ Lp,
                                               float* __restrict__ out,
                                               float* __restrict__ p1) {
    __shared__ short lds[2][16384];             // 2 x 32KB: 16 chunks x 1024 elems

    const int tid = threadIdx.x;
    const int lane = tid & 63;
    const int wvi = tid >> 6;                   // 0..3 ROW-GROUP
    const int lane15 = lane & 15, kg = lane >> 4, koff = kg * 8;
    const int b = (int)blockIdx.x;
    const int rb = b >> 2, fh = (b >> 1) & 1, ks = b & 1;
    const int row0 = rb * 64;
    const int mrow = row0 + wvi * 16 + lane15;
    const int fb = fh * 128;
    const int ksbase = ks * 4096;
    const float si = s1[mrow];
    const float tmx = si + Mrow[mrow];
    const float mC = fmaxf(tmx, 0.2f * tmx) * LOG2E_F;
    const unsigned* __restrict__ mr = mask32 + (size_t)mrow * 256;

    // staging role: 16 chunks x 16 threads; thread loads 8 x 16B
    const int ch = tid >> 4;                    // chunk 0..15
    const int off = (tid & 15) * 8;             // elem offset within chunk

    f32x4 acc[8], accL;
#pragma unroll
    for (int nt = 0; nt < 8; ++nt) { f32x4 z = {0.f, 0.f, 0.f, 0.f}; acc[nt] = z; }
    { f32x4 z = {0.f, 0.f, 0.f, 0.f}; accL = z; }

    s16x8 bones;
#pragma unroll
    for (int j = 0; j < 8; ++j) bones[j] = (short)0x3F80;   // bf16 1.0

    i32x4 sreg[8];
    LOADREGS(0)
    WRITELDS(0)
    LOADREGS(1)
    __syncthreads();

#pragma unroll 1
    for (int t = 0; t < 32; ++t) {              // 32 tiles x 128 keys
        const int cur = t & 1;
        if (t + 1 < 32) WRITELDS(cur ^ 1)       // tile t+1 (regs -> LDS)
        if (t + 2 < 32) LOADREGS(t + 2)         // prefetch tile t+2

        const i32x4 mwv = *(const i32x4*)(mr + ((unsigned)(ksbase + t * 128) >> 5));
        STEP(0) STEP(1) STEP(2) STEP(3)
        __syncthreads();
    }

    // l partials (exact f32 over this ks-half); only fh==0 writes
    if (lane15 == 0 && fh == 0) {
#pragma unroll
        for (int r = 0; r < 4; ++r)
            Lp[(size_t)ks * N_ROWS + row0 + wvi * 16 + kg * 4 + r] = accL[r];
    }

    // direct store (each wave owns its 16 rows; no cross-wave merge)
    float* __restrict__ dst = ks ? p1 : out;
#pragma unroll
    for (int r = 0; r < 4; ++r) {
        const int row = row0 + wvi * 16 + kg * 4 + r;
        float* op = dst + (size_t)row * F_DIM + fb + lane15;
#pragma unroll
        for (int nt = 0; nt < 8; ++nt) op[nt * 16] = acc[nt][r];
    }
}

// ------------- Kernel 3: merge key-halves + normalize --------------------
__global__ __launch_bounds__(256) void k3_merge(float* __restrict__ out,
                                                const float* __restrict__ p1,
                                                const float* __restrict__ Lp) {
    const int idx = (int)blockIdx.x * 256 + threadIdx.x;   // 524288 threads
    const int row = idx >> 6, fc = (idx & 63) * 4;
    const float inv = 1.0f / (Lp[row] + Lp[N_ROWS + row]);
    float* op = out + (size_t)row * F_DIM + fc;
    f32x4 v0 = *(const f32x4*)op;
    f32x4 v1 = *(const f32x4*)(p1 + (size_t)row * F_DIM + fc);
    f32x4 o;
#pragma unroll
    for (int j = 0; j < 4; ++j) o[j] = (v0[j] + v1[j]) * inv;
    *(f32x4*)op = o;
}

extern "C" void kernel_launch(void* const* d_in, const int* in_sizes, int n_in,
                              void* d_out, int out_size, void* d_ws, size_t ws_size,
                              hipStream_t stream) {
    (void)in_sizes; (void)n_in; (void)out_size; (void)ws_size;
    const float* x  = (const float*)d_in[0];
    const int*  adj = (const int*)d_in[1];
    const float* W  = (const float*)d_in[2];
    const float* a  = (const float*)d_in[3];
    float* out = (float*)d_out;
    char* ws = (char*)d_ws;
    // ws use ~20.3 MB (ws_size ~1GB per harness fill evidence)
    unsigned short* hTp = (unsigned short*)ws;                          // 4 MB
    float* s1 = (float*)(ws + (4 << 20));                               // 32 KB
    float* s2 = (float*)(ws + (4 << 20) + (32 << 10));                  // 32 KB
    float* va = (float*)(ws + (4 << 20) + (64 << 10));                  // 2 KB
    float* Mr = (float*)(ws + (4 << 20) + (96 << 10));                  // 32 KB
    float* Lp = (float*)(ws + (4 << 20) + (128 << 10));                 // 64 KB [2][8192]
    unsigned long long* mk = (unsigned long long*)(ws + (4 << 20) + (256 << 10)); // 8 MB
    float* p1 = (float*)(ws + (12 << 20) + (256 << 10));                // 8 MB

    k0_pack<<<4096, 256, 0, stream>>>(adj, mk);
    k1_gemm<<<512, 256, 0, stream>>>(x, W, hTp);
    kva<<<2, 256, 0, stream>>>(W, a, va);
    k1b_s<<<256, 256, 0, stream>>>(x, va, s1, s2);
    kmax<<<2048, 256, 0, stream>>>((const unsigned*)mk, s2, Mr);
    k2_attn<<<512, 256, 0, stream>>>((const unsigned*)mk, hTp, s1, s2, Mr, Lp, out, p1);
    k3_merge<<<2048, 256, 0, stream>>>(out, p1, Lp);
}